// Round 1
// 150.183 us; speedup vs baseline: 1.0154x; 1.0154x over previous
//
#include <hip/hip_runtime.h>
#include <math.h>

namespace {

constexpr int LNUM = 2097152;        // L
constexpr int NROW = 5;              // N
constexpr int NSER = 10;             // rows total (0..4 rppg, 5..9 ppg)
constexpr int TPB = 256;
constexpr int EPL = 16;              // elements per lane (one 64B line)
constexpr int CHUNK = TPB * EPL;     // 4096 per block
constexpr int CPR = LNUM / CHUNK;    // 512 chunks per row
constexpr int NBLK = NSER * CPR;     // 5120
constexpr int MAXC = 688;            // max candidates/chunk (peaks >=6 apart -> <=683)

struct Agg { int first; int last; int c; double s; };

__device__ __forceinline__ Agg combine(const Agg& a, const Agg& b) {
  // ordered segment-concat monoid: a LEFT, b RIGHT (non-commutative)
  Agg r;
  r.first = (a.first >= 0) ? a.first : b.first;
  r.last  = (b.last >= 0) ? b.last : a.last;
  r.s = a.s + b.s;
  r.c = a.c + b.c;
  if (a.last >= 0 && b.first >= 0) {
    r.s += 1.0 / (double)(b.first - a.last);
    r.c += 1;
  }
  return r;
}

// Per-lane: 16 contiguous elements at row-relative offset s (s % 16 == 0).
// Own data = one 64B line via 4x dwordx4; halo +-5 via shuffles from
// neighbor lanes; lanes 0/63 patch halo with guarded global loads (-inf pad
// at row edges). Window-11 max via register doubling (m2/m4/m8).
// X[i] = x[s-5+i]  (i=0..25);  w[t] = max over window centered at X[5+t].
__device__ __forceinline__ void window16(const float* __restrict__ x, int s,
                                         float X[26], float w[16]) {
  const float4* q = reinterpret_cast<const float4*>(x + s);
  float4 f0 = q[0], f1 = q[1], f2 = q[2], f3 = q[3];
  X[5] = f0.x;  X[6] = f0.y;  X[7] = f0.z;  X[8] = f0.w;
  X[9] = f1.x;  X[10] = f1.y; X[11] = f1.z; X[12] = f1.w;
  X[13] = f2.x; X[14] = f2.y; X[15] = f2.z; X[16] = f2.w;
  X[17] = f3.x; X[18] = f3.y; X[19] = f3.z; X[20] = f3.w;
#pragma unroll
  for (int j = 0; j < 5; ++j) X[j] = __shfl_up(X[16 + j], 1);      // x[s-5+j]
#pragma unroll
  for (int j = 0; j < 5; ++j) X[21 + j] = __shfl_down(X[5 + j], 1); // x[s+16+j]
  const int lane = threadIdx.x & 63;
  if (lane == 0) {
#pragma unroll
    for (int j = 0; j < 5; ++j) {
      int g = s - 5 + j;
      X[j] = (g >= 0) ? x[g] : -INFINITY;
    }
  }
  if (lane == 63) {
#pragma unroll
    for (int j = 0; j < 5; ++j) {
      int g = s + 16 + j;
      X[21 + j] = (g < LNUM) ? x[g] : -INFINITY;
    }
  }
  float m2[25];
#pragma unroll
  for (int i = 0; i < 25; ++i) m2[i] = fmaxf(X[i], X[i + 1]);
  float m4[23];
#pragma unroll
  for (int i = 0; i < 23; ++i) m4[i] = fmaxf(m2[i], m2[i + 2]);
  float m8[19];
#pragma unroll
  for (int i = 0; i < 19; ++i) m8[i] = fmaxf(m4[i], m4[i + 4]);
#pragma unroll
  for (int t = 0; t < 16; ++t) w[t] = fmaxf(m8[t], m8[t + 3]);  // X[t..t+10]
}

__device__ __forceinline__ const float* row_ptr(const float* rppg,
                                                const float* ppg, int rw) {
  return (rw < NROW) ? rppg + (size_t)rw * LNUM
                     : ppg + (size_t)(rw - NROW) * LNUM;
}

// Pass 1 (single full-data read): per-chunk {sum, peak-value-sum, peak-count}
// AND materialized candidate-peak list (pos, val-bits) in position order.
// Candidate order = threadIdx order x t order = position order, via
// block-wide exclusive scan of per-lane candidate counts. NO atomics.
__global__ __launch_bounds__(TPB) void stats_collect_kernel(
    const float* __restrict__ rppg, const float* __restrict__ ppg,
    double* __restrict__ psum, double* __restrict__ ppk,
    int* __restrict__ pnpk, int* __restrict__ ccnt,
    int2* __restrict__ cand) {
  const int bid = blockIdx.x;
  const int rw = bid >> 9;          // /CPR
  const int chunk = bid & (CPR - 1);
  const float* x = row_ptr(rppg, ppg, rw);
  const int lane = threadIdx.x & 63;
  const int wid = threadIdx.x >> 6;
  const int s = chunk * CHUNK + wid * (64 * EPL) + lane * EPL;

  float X[26], w[16];
  window16(x, s, X, w);

  double tsum = 0.0, tpk = 0.0;
  int tn = 0;
#pragma unroll
  for (int t = 0; t < 16; ++t) {
    float v = X[5 + t];
    tsum += (double)v;
    if (v == w[t]) { tpk += (double)v; ++tn; }
  }
  const int cnt = tn;  // per-lane candidate count (survives the reduce below)

  // stats reduce
#pragma unroll
  for (int off = 32; off > 0; off >>= 1) {
    tsum += __shfl_down(tsum, off);
    tpk  += __shfl_down(tpk, off);
    tn   += __shfl_down(tn, off);
  }

  // wave-level inclusive scan of cnt for candidate offsets
  int inc = cnt;
#pragma unroll
  for (int off = 1; off < 64; off <<= 1) {
    int u = __shfl_up(inc, off);
    if (lane >= off) inc += u;
  }

  __shared__ double wsum[4], wpk[4];
  __shared__ int wn[4], wtot[4];
  if (lane == 0) { wsum[wid] = tsum; wpk[wid] = tpk; wn[wid] = tn; }
  if (lane == 63) wtot[wid] = inc;
  __syncthreads();

  int wpre = 0;
#pragma unroll
  for (int i = 0; i < 4; ++i) if (i < wid) wpre += wtot[i];
  int off0 = wpre + inc - cnt;  // block-exclusive offset, position-ordered
  const int total = wtot[0] + wtot[1] + wtot[2] + wtot[3];

  int2* cb = cand + (size_t)bid * MAXC;
  int o = off0;
#pragma unroll
  for (int t = 0; t < 16; ++t) {
    float v = X[5 + t];
    if (v == w[t] && o < MAXC) {
      int2 e; e.x = s + t; e.y = __float_as_int(v);
      cb[o] = e;
      ++o;
    }
  }

  if (threadIdx.x == 0) {
    psum[bid] = wsum[0] + wsum[1] + wsum[2] + wsum[3];
    ppk[bid]  = wpk[0] + wpk[1] + wpk[2] + wpk[3];
    pnpk[bid] = wn[0] + wn[1] + wn[2] + wn[3];
    ccnt[bid] = (total < MAXC) ? total : MAXC;
  }
}

// Pass 2: per-chunk ordered gap aggregates FROM THE CANDIDATE LIST only
// (no raw-data re-read). Per-row threshold re-derived per block from the
// 512 chunk partials (10 KB/row, L2-resident). NO atomics.
// x_norm > mean_pk_norm/2  <=>  x > (mu + mean_pk_raw)/2  (affine, sd cancels)
__global__ __launch_bounds__(TPB) void gap_kernel(
    const double* __restrict__ psum, const double* __restrict__ ppk,
    const int* __restrict__ pnpk, const int* __restrict__ ccnt,
    const int2* __restrict__ cand,
    int* __restrict__ cfirst, int* __restrict__ clast,
    double* __restrict__ csum, int* __restrict__ cnum) {
  const int bid = blockIdx.x;
  const int rw = bid >> 9;
  const int t = threadIdx.x;
  const int lane = t & 63;
  const int wid = t >> 6;

  // inline per-row threshold from chunk partials
  double s0 = psum[rw * CPR + t] + psum[rw * CPR + t + 256];
  double p0 = ppk[rw * CPR + t] + ppk[rw * CPR + t + 256];
  int n0 = pnpk[rw * CPR + t] + pnpk[rw * CPR + t + 256];
#pragma unroll
  for (int off = 32; off > 0; off >>= 1) {
    s0 += __shfl_down(s0, off);
    p0 += __shfl_down(p0, off);
    n0 += __shfl_down(n0, off);
  }
  __shared__ double ws_[4], wp_[4];
  __shared__ int wn_[4];
  __shared__ double sthr;
  if (lane == 0) { ws_[wid] = s0; wp_[wid] = p0; wn_[wid] = n0; }
  __syncthreads();
  if (t == 0) {
    double S = ws_[0] + ws_[1] + ws_[2] + ws_[3];
    double P = wp_[0] + wp_[1] + wp_[2] + wp_[3];
    double Nn = (double)(wn_[0] + wn_[1] + wn_[2] + wn_[3]);
    sthr = 0.5 * (S / (double)LNUM + P / Nn);
  }
  __syncthreads();
  const float th = (float)sthr;

  // candidates: thread t owns the (ordered) triple {3t, 3t+1, 3t+2}
  const int cnt = ccnt[bid];
  const int2* cb = cand + (size_t)bid * MAXC;

  Agg a; a.first = -1; a.last = -1; a.c = 0; a.s = 0.0;
#pragma unroll
  for (int j = 0; j < 3; ++j) {
    int idx = 3 * t + j;
    if (idx < cnt) {
      int2 e = cb[idx];
      float v = __int_as_float(e.y);
      if (v > th) {
        int p = e.x;
        if (a.last >= 0) { a.s += 1.0 / (double)(p - a.last); ++a.c; }
        else a.first = p;
        a.last = p;
      }
    }
  }
  // ordered wave tree: lane i's segment is immediately left of lane i+off's
#pragma unroll
  for (int off = 1; off < 64; off <<= 1) {
    Agg b;
    b.first = __shfl_down(a.first, off);
    b.last  = __shfl_down(a.last, off);
    b.c     = __shfl_down(a.c, off);
    b.s     = __shfl_down(a.s, off);
    a = combine(a, b);
  }

  __shared__ Agg waggs[4];
  if (lane == 0) waggs[wid] = a;
  __syncthreads();
  if (t == 0) {
    Agg r = waggs[0];
    r = combine(r, waggs[1]);
    r = combine(r, waggs[2]);
    r = combine(r, waggs[3]);
    cfirst[bid] = r.first; clast[bid] = r.last;
    csum[bid] = r.s; cnum[bid] = r.c;
  }
}

// Final: one block; per row combine the 512 chunk Aggs in order -> hr,
// then the score. Thread t covers chunks {2t, 2t+1} (segment order = lane
// order within each wave; waves combined in order afterwards).
__global__ __launch_bounds__(TPB) void final_kernel(
    const int* __restrict__ cfirst, const int* __restrict__ clast,
    const double* __restrict__ csum, const int* __restrict__ cnum,
    const int* __restrict__ fsp, float* __restrict__ out) {
  __shared__ Agg waggs[4];
  __shared__ double shr[NSER];
  const int t = threadIdx.x;
  const int lane = t & 63;
  const int wid = t >> 6;
  for (int r = 0; r < NSER; ++r) {
    const int i0 = r * CPR + 2 * t;
    Agg a0; a0.first = cfirst[i0];     a0.last = clast[i0];
    a0.c = cnum[i0];                   a0.s = csum[i0];
    Agg a1; a1.first = cfirst[i0 + 1]; a1.last = clast[i0 + 1];
    a1.c = cnum[i0 + 1];               a1.s = csum[i0 + 1];
    a0 = combine(a0, a1);
#pragma unroll
    for (int off = 1; off < 64; off <<= 1) {
      Agg b;
      b.first = __shfl_down(a0.first, off);
      b.last  = __shfl_down(a0.last, off);
      b.c     = __shfl_down(a0.c, off);
      b.s     = __shfl_down(a0.s, off);
      a0 = combine(a0, b);
    }
    if (lane == 0) waggs[wid] = a0;
    __syncthreads();
    if (t == 0) {
      Agg rr = waggs[0];
      rr = combine(rr, waggs[1]);
      rr = combine(rr, waggs[2]);
      rr = combine(rr, waggs[3]);
      shr[r] = 60.0 * (double)fsp[0] * rr.s / (double)rr.c;
    }
    __syncthreads();
  }
  if (t == 0) {
    double acc = 0.0;
    for (int r = 0; r < NROW; ++r)
      acc += fabs(shr[NROW + r] - shr[r]) / shr[NROW + r];
    out[0] = (float)(acc / (double)NROW);
  }
}

}  // namespace

extern "C" void kernel_launch(void* const* d_in, const int* in_sizes, int n_in,
                              void* d_out, int out_size, void* d_ws, size_t ws_size,
                              hipStream_t stream) {
  const float* rppg = (const float*)d_in[0];
  const float* ppg  = (const float*)d_in[1];
  const int* fsp    = (const int*)d_in[2];
  float* out        = (float*)d_out;
  char* ws          = (char*)d_ws;

  // ws layout (all 8-aligned)
  double* psum   = (double*)(ws);            // 5120*8  = 40960
  double* ppk    = (double*)(ws + 40960);    // 40960   -> 81920
  int*    pnpk   = (int*)(ws + 81920);       // 20480   -> 102400
  int*    ccnt   = (int*)(ws + 102400);      // 20480   -> 122880
  double* csum   = (double*)(ws + 122880);   // 40960   -> 163840
  int*    cfirst = (int*)(ws + 163840);      // 20480   -> 184320
  int*    clast  = (int*)(ws + 184320);      // 20480   -> 204800
  int*    cnum   = (int*)(ws + 204800);      // 20480   -> 225280
  int2*   cand   = (int2*)(ws + 225280);     // 5120*688*8 = 28180480 -> ~28.4 MB

  stats_collect_kernel<<<NBLK, TPB, 0, stream>>>(rppg, ppg, psum, ppk, pnpk,
                                                 ccnt, cand);
  gap_kernel<<<NBLK, TPB, 0, stream>>>(psum, ppk, pnpk, ccnt, cand,
                                       cfirst, clast, csum, cnum);
  final_kernel<<<1, TPB, 0, stream>>>(cfirst, clast, csum, cnum, fsp, out);
  (void)in_sizes; (void)n_in; (void)out_size; (void)ws_size;
}

// Round 2
// 149.965 us; speedup vs baseline: 1.0169x; 1.0015x over previous
//
#include <hip/hip_runtime.h>
#include <hip/hip_cooperative_groups.h>
#include <math.h>

namespace cg = cooperative_groups;

namespace {

constexpr int LNUM = 2097152;        // L
constexpr int NROW = 5;              // N
constexpr int NSER = 10;             // rows total (0..4 rppg, 5..9 ppg)
constexpr int TPB = 256;
constexpr int EPL = 16;              // elements per lane (one 64B line)
constexpr int SUB = TPB * EPL;       // 4096 per sub-chunk
constexpr int NSUB = 4;              // sub-chunks per block (fused path)
constexpr int CHUNKB = SUB * NSUB;   // 16384 per block
constexpr int CPRB = LNUM / CHUNKB;  // 128 chunks per row
constexpr int NBLKC = NSER * CPRB;   // 1280 blocks (== 5 per CU on 256 CUs)
constexpr int MAXC = 2752;           // LDS candidate cap (16384/6 = 2731)

// fallback (3-kernel) geometry
constexpr int CHUNK = SUB;           // 4096
constexpr int CPR = LNUM / CHUNK;    // 512
constexpr int NBLK = NSER * CPR;     // 5120
constexpr int MAXCF = 688;

struct Agg { int first; int last; int c; double s; };

__device__ __forceinline__ Agg combine(const Agg& a, const Agg& b) {
  // ordered segment-concat monoid: a LEFT, b RIGHT (non-commutative)
  Agg r;
  r.first = (a.first >= 0) ? a.first : b.first;
  r.last  = (b.last >= 0) ? b.last : a.last;
  r.s = a.s + b.s;
  r.c = a.c + b.c;
  if (a.last >= 0 && b.first >= 0) {
    r.s += 1.0 / (double)(b.first - a.last);
    r.c += 1;
  }
  return r;
}

// Per-lane: 16 contiguous elements at row-relative offset s (s % 16 == 0).
// Own data = one 64B line via 4x dwordx4; halo +-5 via shuffles from
// neighbor lanes; lanes 0/63 patch halo with guarded global loads (-inf pad
// at row edges). Window-11 max via register doubling (m2/m4/m8).
// X[i] = x[s-5+i]  (i=0..25);  w[t] = max over window centered at X[5+t].
__device__ __forceinline__ void window16(const float* __restrict__ x, int s,
                                         float X[26], float w[16]) {
  const float4* q = reinterpret_cast<const float4*>(x + s);
  float4 f0 = q[0], f1 = q[1], f2 = q[2], f3 = q[3];
  X[5] = f0.x;  X[6] = f0.y;  X[7] = f0.z;  X[8] = f0.w;
  X[9] = f1.x;  X[10] = f1.y; X[11] = f1.z; X[12] = f1.w;
  X[13] = f2.x; X[14] = f2.y; X[15] = f2.z; X[16] = f2.w;
  X[17] = f3.x; X[18] = f3.y; X[19] = f3.z; X[20] = f3.w;
#pragma unroll
  for (int j = 0; j < 5; ++j) X[j] = __shfl_up(X[16 + j], 1);      // x[s-5+j]
#pragma unroll
  for (int j = 0; j < 5; ++j) X[21 + j] = __shfl_down(X[5 + j], 1); // x[s+16+j]
  const int lane = threadIdx.x & 63;
  if (lane == 0) {
#pragma unroll
    for (int j = 0; j < 5; ++j) {
      int g = s - 5 + j;
      X[j] = (g >= 0) ? x[g] : -INFINITY;
    }
  }
  if (lane == 63) {
#pragma unroll
    for (int j = 0; j < 5; ++j) {
      int g = s + 16 + j;
      X[21 + j] = (g < LNUM) ? x[g] : -INFINITY;
    }
  }
  float m2[25];
#pragma unroll
  for (int i = 0; i < 25; ++i) m2[i] = fmaxf(X[i], X[i + 1]);
  float m4[23];
#pragma unroll
  for (int i = 0; i < 23; ++i) m4[i] = fmaxf(m2[i], m2[i + 2]);
  float m8[19];
#pragma unroll
  for (int i = 0; i < 19; ++i) m8[i] = fmaxf(m4[i], m4[i + 4]);
#pragma unroll
  for (int t = 0; t < 16; ++t) w[t] = fmaxf(m8[t], m8[t + 3]);  // X[t..t+10]
}

__device__ __forceinline__ const float* row_ptr(const float* rppg,
                                                const float* ppg, int rw) {
  return (rw < NROW) ? rppg + (size_t)rw * LNUM
                     : ppg + (size_t)(rw - NROW) * LNUM;
}

// ---------------------------------------------------------------------------
// Fused cooperative kernel: one launch, candidates live in LDS only.
// Phase 1: stream 16K elems/block -> per-chunk {sum, pksum, npk} partials +
//          LDS candidate list (position order via block scan).
// grid.sync()
// Phase 2: per-row threshold from 128 partials (redundant per block, L2-hot),
//          filter LDS candidates, ordered Agg -> 24B/block to global.
// grid.sync()
// Phase 3: block 0 combines 128 Aggs/row -> hr -> score.
// ---------------------------------------------------------------------------
__global__ __launch_bounds__(TPB, 5) void fused_kernel(
    const float* __restrict__ rppg, const float* __restrict__ ppg,
    const int* __restrict__ fsp,
    double* __restrict__ psum, double* __restrict__ ppk,
    int* __restrict__ pnpk,
    int* __restrict__ afirst, int* __restrict__ alast,
    double* __restrict__ asum, int* __restrict__ acnt,
    float* __restrict__ out) {
  cg::grid_group gridg = cg::this_grid();

  __shared__ int2 cand[MAXC];
  __shared__ double wsum[4], wpk[4];
  __shared__ int wn[4], wtot[4];
  __shared__ Agg waggs[4];
  __shared__ double shr[NSER];

  const int bid = blockIdx.x;
  const int rw = bid >> 7;             // / CPRB
  const int chunk = bid & (CPRB - 1);
  const float* x = row_ptr(rppg, ppg, rw);
  const int lane = threadIdx.x & 63;
  const int wid = threadIdx.x >> 6;

  // ---- Phase 1 ----
  double tsum = 0.0, tpk = 0.0;
  int tn = 0;
  int base = 0;  // uniform across block (same arithmetic everywhere)
  for (int k = 0; k < NSUB; ++k) {
    const int s = chunk * CHUNKB + k * SUB + wid * (64 * EPL) + lane * EPL;
    float X[26], w[16];
    window16(x, s, X, w);
    int cnt = 0;
#pragma unroll
    for (int t = 0; t < 16; ++t) {
      float v = X[5 + t];
      tsum += (double)v;
      if (v == w[t]) { tpk += (double)v; ++tn; ++cnt; }
    }
    // wave inclusive scan of cnt
    int inc = cnt;
#pragma unroll
    for (int off = 1; off < 64; off <<= 1) {
      int u = __shfl_up(inc, off);
      if (lane >= off) inc += u;
    }
    if (lane == 63) wtot[wid] = inc;
    __syncthreads();
    int wpre = 0;
#pragma unroll
    for (int i = 0; i < 4; ++i) if (i < wid) wpre += wtot[i];
    const int off0 = base + wpre + inc - cnt;
    const int total = wtot[0] + wtot[1] + wtot[2] + wtot[3];
    int o = off0;
#pragma unroll
    for (int t = 0; t < 16; ++t) {
      float v = X[5 + t];
      if (v == w[t] && o < MAXC) {
        int2 e; e.x = s + t; e.y = __float_as_int(v);
        cand[o] = e;
        ++o;
      }
    }
    base += total;
    __syncthreads();  // wtot reused next sub; cand writes complete
  }
  const int scnt = (base < MAXC) ? base : MAXC;

  // block stats reduce
#pragma unroll
  for (int off = 32; off > 0; off >>= 1) {
    tsum += __shfl_down(tsum, off);
    tpk  += __shfl_down(tpk, off);
    tn   += __shfl_down(tn, off);
  }
  if (lane == 0) { wsum[wid] = tsum; wpk[wid] = tpk; wn[wid] = tn; }
  __syncthreads();
  if (threadIdx.x == 0) {
    psum[bid] = wsum[0] + wsum[1] + wsum[2] + wsum[3];
    ppk[bid]  = wpk[0] + wpk[1] + wpk[2] + wpk[3];
    pnpk[bid] = wn[0] + wn[1] + wn[2] + wn[3];
  }

  gridg.sync();

  // ---- Phase 2: row threshold (redundant per block; 2.5 KB coalesced) ----
  double s0 = 0.0, p0 = 0.0;
  int n0 = 0;
  if (threadIdx.x < CPRB) {
    const int i = rw * CPRB + threadIdx.x;
    s0 = psum[i]; p0 = ppk[i]; n0 = pnpk[i];
  }
#pragma unroll
  for (int off = 32; off > 0; off >>= 1) {
    s0 += __shfl_down(s0, off);
    p0 += __shfl_down(p0, off);
    n0 += __shfl_down(n0, off);
  }
  if (lane == 0) { wsum[wid] = s0; wpk[wid] = p0; wn[wid] = n0; }
  __syncthreads();
  const double S = wsum[0] + wsum[1] + wsum[2] + wsum[3];
  const double P = wpk[0] + wpk[1] + wpk[2] + wpk[3];
  const double Nn = (double)(wn[0] + wn[1] + wn[2] + wn[3]);
  // x_norm > mean_pk_norm/2  <=>  x > (mu + mean_pk_raw)/2  (affine, sd cancels)
  const float th = (float)(0.5 * (S / (double)LNUM + P / Nn));

  // filter LDS candidates, ordered Agg: thread t owns [t*q, t*q+q)
  const int q = (scnt + TPB - 1) / TPB;
  Agg a; a.first = -1; a.last = -1; a.c = 0; a.s = 0.0;
  for (int j = 0; j < q; ++j) {
    const int idx = threadIdx.x * q + j;
    if (idx < scnt) {
      int2 e = cand[idx];
      float v = __int_as_float(e.y);
      if (v > th) {
        int p = e.x;
        if (a.last >= 0) { a.s += 1.0 / (double)(p - a.last); ++a.c; }
        else a.first = p;
        a.last = p;
      }
    }
  }
#pragma unroll
  for (int off = 1; off < 64; off <<= 1) {
    Agg b;
    b.first = __shfl_down(a.first, off);
    b.last  = __shfl_down(a.last, off);
    b.c     = __shfl_down(a.c, off);
    b.s     = __shfl_down(a.s, off);
    a = combine(a, b);
  }
  if (lane == 0) waggs[wid] = a;
  __syncthreads();
  if (threadIdx.x == 0) {
    Agg r = waggs[0];
    r = combine(r, waggs[1]);
    r = combine(r, waggs[2]);
    r = combine(r, waggs[3]);
    afirst[bid] = r.first; alast[bid] = r.last;
    asum[bid] = r.s; acnt[bid] = r.c;
  }

  gridg.sync();

  // ---- Phase 3: block 0 only ----
  if (bid == 0) {
    for (int r = 0; r < NSER; ++r) {
      Agg a0; a0.first = -1; a0.last = -1; a0.c = 0; a0.s = 0.0;
      if (threadIdx.x < CPRB) {
        const int i = r * CPRB + threadIdx.x;
        a0.first = afirst[i]; a0.last = alast[i];
        a0.c = acnt[i];       a0.s = asum[i];
      }
#pragma unroll
      for (int off = 1; off < 64; off <<= 1) {
        Agg b;
        b.first = __shfl_down(a0.first, off);
        b.last  = __shfl_down(a0.last, off);
        b.c     = __shfl_down(a0.c, off);
        b.s     = __shfl_down(a0.s, off);
        a0 = combine(a0, b);
      }
      if (lane == 0) waggs[wid] = a0;
      __syncthreads();
      if (threadIdx.x == 0) {
        Agg rr = waggs[0];
        rr = combine(rr, waggs[1]);
        rr = combine(rr, waggs[2]);
        rr = combine(rr, waggs[3]);
        shr[r] = 60.0 * (double)fsp[0] * rr.s / (double)rr.c;
      }
      __syncthreads();
    }
    if (threadIdx.x == 0) {
      double acc = 0.0;
      for (int r = 0; r < NROW; ++r)
        acc += fabs(shr[NROW + r] - shr[r]) / shr[NROW + r];
      out[0] = (float)(acc / (double)NROW);
    }
  }
}

// ---------------------------------------------------------------------------
// Fallback path (proven round-1 kernels) in case cooperative occupancy fails.
// ---------------------------------------------------------------------------
__global__ __launch_bounds__(TPB) void stats_collect_kernel(
    const float* __restrict__ rppg, const float* __restrict__ ppg,
    double* __restrict__ psum, double* __restrict__ ppk,
    int* __restrict__ pnpk, int* __restrict__ ccnt,
    int2* __restrict__ cand) {
  const int bid = blockIdx.x;
  const int rw = bid >> 9;          // /CPR
  const int chunk = bid & (CPR - 1);
  const float* x = row_ptr(rppg, ppg, rw);
  const int lane = threadIdx.x & 63;
  const int wid = threadIdx.x >> 6;
  const int s = chunk * CHUNK + wid * (64 * EPL) + lane * EPL;

  float X[26], w[16];
  window16(x, s, X, w);

  double tsum = 0.0, tpk = 0.0;
  int tn = 0;
#pragma unroll
  for (int t = 0; t < 16; ++t) {
    float v = X[5 + t];
    tsum += (double)v;
    if (v == w[t]) { tpk += (double)v; ++tn; }
  }
  const int cnt = tn;
#pragma unroll
  for (int off = 32; off > 0; off >>= 1) {
    tsum += __shfl_down(tsum, off);
    tpk  += __shfl_down(tpk, off);
    tn   += __shfl_down(tn, off);
  }
  int inc = cnt;
#pragma unroll
  for (int off = 1; off < 64; off <<= 1) {
    int u = __shfl_up(inc, off);
    if (lane >= off) inc += u;
  }
  __shared__ double wsum[4], wpk[4];
  __shared__ int wn[4], wtot[4];
  if (lane == 0) { wsum[wid] = tsum; wpk[wid] = tpk; wn[wid] = tn; }
  if (lane == 63) wtot[wid] = inc;
  __syncthreads();
  int wpre = 0;
#pragma unroll
  for (int i = 0; i < 4; ++i) if (i < wid) wpre += wtot[i];
  int off0 = wpre + inc - cnt;
  const int total = wtot[0] + wtot[1] + wtot[2] + wtot[3];
  int2* cb = cand + (size_t)bid * MAXCF;
  int o = off0;
#pragma unroll
  for (int t = 0; t < 16; ++t) {
    float v = X[5 + t];
    if (v == w[t] && o < MAXCF) {
      int2 e; e.x = s + t; e.y = __float_as_int(v);
      cb[o] = e;
      ++o;
    }
  }
  if (threadIdx.x == 0) {
    psum[bid] = wsum[0] + wsum[1] + wsum[2] + wsum[3];
    ppk[bid]  = wpk[0] + wpk[1] + wpk[2] + wpk[3];
    pnpk[bid] = wn[0] + wn[1] + wn[2] + wn[3];
    ccnt[bid] = (total < MAXCF) ? total : MAXCF;
  }
}

__global__ __launch_bounds__(TPB) void gap_kernel(
    const double* __restrict__ psum, const double* __restrict__ ppk,
    const int* __restrict__ pnpk, const int* __restrict__ ccnt,
    const int2* __restrict__ cand,
    int* __restrict__ cfirst, int* __restrict__ clast,
    double* __restrict__ csum, int* __restrict__ cnum) {
  const int bid = blockIdx.x;
  const int rw = bid >> 9;
  const int t = threadIdx.x;
  const int lane = t & 63;
  const int wid = t >> 6;
  double s0 = psum[rw * CPR + t] + psum[rw * CPR + t + 256];
  double p0 = ppk[rw * CPR + t] + ppk[rw * CPR + t + 256];
  int n0 = pnpk[rw * CPR + t] + pnpk[rw * CPR + t + 256];
#pragma unroll
  for (int off = 32; off > 0; off >>= 1) {
    s0 += __shfl_down(s0, off);
    p0 += __shfl_down(p0, off);
    n0 += __shfl_down(n0, off);
  }
  __shared__ double ws_[4], wp_[4];
  __shared__ int wn_[4];
  __shared__ double sthr;
  if (lane == 0) { ws_[wid] = s0; wp_[wid] = p0; wn_[wid] = n0; }
  __syncthreads();
  if (t == 0) {
    double S = ws_[0] + ws_[1] + ws_[2] + ws_[3];
    double P = wp_[0] + wp_[1] + wp_[2] + wp_[3];
    double Nn = (double)(wn_[0] + wn_[1] + wn_[2] + wn_[3]);
    sthr = 0.5 * (S / (double)LNUM + P / Nn);
  }
  __syncthreads();
  const float th = (float)sthr;
  const int cnt = ccnt[bid];
  const int2* cb = cand + (size_t)bid * MAXCF;
  Agg a; a.first = -1; a.last = -1; a.c = 0; a.s = 0.0;
#pragma unroll
  for (int j = 0; j < 3; ++j) {
    int idx = 3 * t + j;
    if (idx < cnt) {
      int2 e = cb[idx];
      float v = __int_as_float(e.y);
      if (v > th) {
        int p = e.x;
        if (a.last >= 0) { a.s += 1.0 / (double)(p - a.last); ++a.c; }
        else a.first = p;
        a.last = p;
      }
    }
  }
#pragma unroll
  for (int off = 1; off < 64; off <<= 1) {
    Agg b;
    b.first = __shfl_down(a.first, off);
    b.last  = __shfl_down(a.last, off);
    b.c     = __shfl_down(a.c, off);
    b.s     = __shfl_down(a.s, off);
    a = combine(a, b);
  }
  __shared__ Agg waggs[4];
  if (lane == 0) waggs[wid] = a;
  __syncthreads();
  if (t == 0) {
    Agg r = waggs[0];
    r = combine(r, waggs[1]);
    r = combine(r, waggs[2]);
    r = combine(r, waggs[3]);
    cfirst[bid] = r.first; clast[bid] = r.last;
    csum[bid] = r.s; cnum[bid] = r.c;
  }
}

__global__ __launch_bounds__(TPB) void final_kernel(
    const int* __restrict__ cfirst, const int* __restrict__ clast,
    const double* __restrict__ csum, const int* __restrict__ cnum,
    const int* __restrict__ fsp, float* __restrict__ out) {
  __shared__ Agg waggs[4];
  __shared__ double shr[NSER];
  const int t = threadIdx.x;
  const int lane = t & 63;
  const int wid = t >> 6;
  for (int r = 0; r < NSER; ++r) {
    const int i0 = r * CPR + 2 * t;
    Agg a0; a0.first = cfirst[i0];     a0.last = clast[i0];
    a0.c = cnum[i0];                   a0.s = csum[i0];
    Agg a1; a1.first = cfirst[i0 + 1]; a1.last = clast[i0 + 1];
    a1.c = cnum[i0 + 1];               a1.s = csum[i0 + 1];
    a0 = combine(a0, a1);
#pragma unroll
    for (int off = 1; off < 64; off <<= 1) {
      Agg b;
      b.first = __shfl_down(a0.first, off);
      b.last  = __shfl_down(a0.last, off);
      b.c     = __shfl_down(a0.c, off);
      b.s     = __shfl_down(a0.s, off);
      a0 = combine(a0, b);
    }
    if (lane == 0) waggs[wid] = a0;
    __syncthreads();
    if (t == 0) {
      Agg rr = waggs[0];
      rr = combine(rr, waggs[1]);
      rr = combine(rr, waggs[2]);
      rr = combine(rr, waggs[3]);
      shr[r] = 60.0 * (double)fsp[0] * rr.s / (double)rr.c;
    }
    __syncthreads();
  }
  if (t == 0) {
    double acc = 0.0;
    for (int r = 0; r < NROW; ++r)
      acc += fabs(shr[NROW + r] - shr[r]) / shr[NROW + r];
    out[0] = (float)(acc / (double)NROW);
  }
}

}  // namespace

extern "C" void kernel_launch(void* const* d_in, const int* in_sizes, int n_in,
                              void* d_out, int out_size, void* d_ws, size_t ws_size,
                              hipStream_t stream) {
  const float* rppg = (const float*)d_in[0];
  const float* ppg  = (const float*)d_in[1];
  const int* fsp    = (const int*)d_in[2];
  float* out        = (float*)d_out;
  char* ws          = (char*)d_ws;

  // one-time host-side occupancy check (no stream ops; graph-capture safe)
  static int coop_ok = -1;
  if (coop_ok < 0) {
    int nb = 0;
    hipError_t e = hipOccupancyMaxActiveBlocksPerMultiprocessor(
        &nb, reinterpret_cast<const void*>(fused_kernel), TPB, 0);
    coop_ok = (e == hipSuccess && nb >= 5) ? 1 : 0;  // need 5 blocks/CU x 256 CUs
  }

  if (coop_ok) {
    // fused ws layout (all 8-aligned): ~51 KB total
    double* psum   = (double*)(ws);            // 1280*8 = 10240
    double* ppk    = (double*)(ws + 10240);    // 10240  -> 20480
    int*    pnpk   = (int*)(ws + 20480);       // 5120   -> 25600
    int*    afirst = (int*)(ws + 25600);       // 5120   -> 30720
    int*    alast  = (int*)(ws + 30720);       // 5120   -> 35840
    double* asum   = (double*)(ws + 35840);    // 10240  -> 46080
    int*    acnt   = (int*)(ws + 46080);       // 5120   -> 51200

    void* args[] = {
        (void*)&rppg, (void*)&ppg, (void*)&fsp,
        (void*)&psum, (void*)&ppk, (void*)&pnpk,
        (void*)&afirst, (void*)&alast, (void*)&asum, (void*)&acnt,
        (void*)&out};
    hipLaunchCooperativeKernel(reinterpret_cast<const void*>(fused_kernel),
                               dim3(NBLKC), dim3(TPB), args, 0, stream);
  } else {
    // fallback: proven 3-kernel path
    double* psum   = (double*)(ws);            // 5120*8  = 40960
    double* ppk    = (double*)(ws + 40960);    // 40960   -> 81920
    int*    pnpk   = (int*)(ws + 81920);       // 20480   -> 102400
    int*    ccnt   = (int*)(ws + 102400);      // 20480   -> 122880
    double* csum   = (double*)(ws + 122880);   // 40960   -> 163840
    int*    cfirst = (int*)(ws + 163840);      // 20480   -> 184320
    int*    clast  = (int*)(ws + 184320);      // 20480   -> 204800
    int*    cnum   = (int*)(ws + 204800);      // 20480   -> 225280
    int2*   cand   = (int2*)(ws + 225280);     // 5120*688*8 -> ~28.4 MB

    stats_collect_kernel<<<NBLK, TPB, 0, stream>>>(rppg, ppg, psum, ppk, pnpk,
                                                   ccnt, cand);
    gap_kernel<<<NBLK, TPB, 0, stream>>>(psum, ppk, pnpk, ccnt, cand,
                                         cfirst, clast, csum, cnum);
    final_kernel<<<1, TPB, 0, stream>>>(cfirst, clast, csum, cnum, fsp, out);
  }
  (void)in_sizes; (void)n_in; (void)out_size; (void)ws_size;
}